// Round 13
// baseline (57.945 us; speedup 1.0000x reference)
//
#include <hip/hip_runtime.h>

#define WALK_LEN 40
#define WINDOW   5
#define NPAIRS   370
#define BATCHSZ  512
#define NEGK     5
#define NPOS     (BATCHSZ * NPAIRS)        // 189440
#define EMB      128
#define NQ       (BATCHSZ * WALK_LEN)      // 20480 flat-walk rows
#define THREADS  512
#define SBLOCKS  (NPOS / (THREADS / 8))    // 2960 (exact, no tail)

struct PairTab { short src[NPAIRS]; short dst[NPAIRS]; };

constexpr PairTab make_pairs() {
    PairTab t{};
    int k = 0;
    for (int i = 0; i < WALK_LEN; ++i) {
        int lo = (i - WINDOW > 0) ? (i - WINDOW) : 0;
        for (int j = lo; j < i; ++j) { t.src[k] = (short)j; t.dst[k] = (short)i; ++k; }
        int hi = (i + 1 + WINDOW < WALK_LEN) ? (i + 1 + WINDOW) : WALK_LEN;
        for (int j = i + 1; j < hi; ++j) { t.src[k] = (short)j; t.dst[k] = (short)i; ++k; }
    }
    return t;
}

__constant__ PairTab g_pairs = make_pairs();

__device__ __forceinline__ unsigned short bf16rn(float f) {
    unsigned u = __float_as_uint(f);
    u += 0x7fffu + ((u >> 16) & 1u);
    return (unsigned short)(u >> 16);
}

// fast softplus: log(1+e^x); |err| ~1e-7 for x in [-6,6]
__device__ __forceinline__ float softplus_fast(float x) {
    return __logf(1.0f + __expf(x));
}

// 8-lane-group butterfly sum, ALL-DPP (no LDS pipe):
// xor1, xor2 via quad_perm; then ROW_HALF_MIRROR (lane -> lane^7 within each
// 8-lane half-row). After xor1+xor2 each lane holds its quad's sum (invariant
// under xor1/xor2), so the mirrored lane (other quad) supplies the other
// quad-sum: result = full 8-lane sum on every lane.
template <int CTRL>
__device__ __forceinline__ float dpp_add(float x) {
    int y = __builtin_amdgcn_update_dpp(0, __float_as_int(x), CTRL, 0xF, 0xF, true);
    return x + __int_as_float(y);
}
__device__ __forceinline__ float grp8_sum(float d) {
    d = dpp_add<0xB1>(d);     // quad_perm [1,0,3,2] == xor 1
    d = dpp_add<0x4E>(d);     // quad_perm [2,3,0,1] == xor 2
    d = dpp_add<0x141>(d);    // ROW_HALF_MIRROR == xor 7 (other quad's sum)
    return d;
}

// unpack uint4 (8 bf16) -> 8 f32 (static indices -> registers)
#define UNPACK_U4(u, f, base)                                         \
    do {                                                              \
        _Pragma("unroll")                                             \
        for (int _i = 0; _i < 4; ++_i) {                              \
            const unsigned _v = (&(u).x)[_i];                         \
            (f)[(base) + 2 * _i]     = __uint_as_float(_v << 16);     \
            (f)[(base) + 2 * _i + 1] = __uint_as_float(_v & 0xffff0000u); \
        }                                                             \
    } while (0)

// dot of pre-unpacked 16 floats against packed bf16 rows xa,xb: 4 fma trees
__device__ __forceinline__ float dot_pk(const float* nf, uint4 xa, uint4 xb) {
    float s0 = 0.f, s1 = 0.f, s2 = 0.f, s3 = 0.f;
    #pragma unroll
    for (int i = 0; i < 4; ++i) {
        const unsigned v = (&xa.x)[i];
        s0 = fmaf(__uint_as_float(v << 16),          nf[2 * i],     s0);
        s1 = fmaf(__uint_as_float(v & 0xffff0000u),  nf[2 * i + 1], s1);
    }
    #pragma unroll
    for (int i = 0; i < 4; ++i) {
        const unsigned v = (&xb.x)[i];
        s2 = fmaf(__uint_as_float(v << 16),          nf[8 + 2 * i],     s2);
        s3 = fmaf(__uint_as_float(v & 0xffff0000u),  nf[8 + 2 * i + 1], s3);
    }
    return (s0 + s1) + (s2 + s3);
}

// ---- phase 1 (== R10): gather flat-walk rows into dense bf16, both tables ----
__global__ __launch_bounds__(256) void dw_gather(
    const int*   __restrict__ walk,
    const float* __restrict__ nodeE,
    const float* __restrict__ ctxE,
    unsigned short* __restrict__ dN,
    unsigned short* __restrict__ dC,
    float* __restrict__ out)
{
    if (blockIdx.x == 0 && threadIdx.x == 0) out[0] = 0.f;
    int idx = blockIdx.x * 256 + threadIdx.x;      // 0 .. 2*NQ*32-1
    const int is_ctx = (idx >= NQ * 32);
    if (is_ctx) idx -= NQ * 32;
    const int q = idx >> 5, c = idx & 31;
    const int row = walk[q];
    const float* src = (is_ctx ? ctxE : nodeE) + (size_t)row * EMB;
    const float4 v = *((const float4*)src + c);
    ushort4 o;
    o.x = bf16rn(v.x); o.y = bf16rn(v.y); o.z = bf16rn(v.z); o.w = bf16rn(v.w);
    unsigned short* dst = (is_ctx ? dC : dN) + (size_t)q * EMB;
    *((ushort4*)dst + c) = o;
}

// ---- phase 2: FLAT — one 8-lane group per pair, no LDS, no loop, no tail ----
// a/c/n rows read directly from the dense bf16 buffers (L2-resident, 10.5 MB;
// adjacent groups are same-batch pairs -> strong L1 reuse of the 40-row set).
__global__ __launch_bounds__(THREADS) void dw_score(
    const int* __restrict__ negdst,                 // [NPOS*NEGK] -> dense row id
    const unsigned short* __restrict__ dN,
    const unsigned short* __restrict__ dC,
    float* __restrict__ out)
{
    const int tid   = threadIdx.x;
    const int lane8 = tid & 7;
    const int pid   = (blockIdx.x * THREADS + tid) >> 3;   // 0..NPOS-1

    const int b  = pid / NPAIRS;
    const int j  = pid - b * NPAIRS;
    const int arow = b * WALK_LEN + g_pairs.src[j];
    const int drow = b * WALK_LEN + g_pairs.dst[j];

    const int* nb = negdst + pid * NEGK;
    const int q0 = nb[0], q1 = nb[1], q2 = nb[2], q3 = nb[3], q4 = nb[4];

    // issue ALL loads up front (16 independent uint4 = 128B segments)
    const uint4* gA = (const uint4*)(dN + (size_t)arow * EMB);
    const uint4* gC = (const uint4*)(dC + (size_t)drow * EMB);
    const uint4* gS = (const uint4*)(dN + (size_t)drow * EMB);
    const uint4* g0 = (const uint4*)(dC + (size_t)q0 * EMB);
    const uint4* g1 = (const uint4*)(dC + (size_t)q1 * EMB);
    const uint4* g2 = (const uint4*)(dC + (size_t)q2 * EMB);
    const uint4* g3 = (const uint4*)(dC + (size_t)q3 * EMB);
    const uint4* g4 = (const uint4*)(dC + (size_t)q4 * EMB);
    const uint4 a0  = gA[lane8], a1  = gA[lane8 + 8];
    const uint4 c0  = gC[lane8], c1  = gC[lane8 + 8];
    const uint4 n0  = gS[lane8], n1  = gS[lane8 + 8];
    const uint4 x00 = g0[lane8], x01 = g0[lane8 + 8];
    const uint4 x10 = g1[lane8], x11 = g1[lane8 + 8];
    const uint4 x20 = g2[lane8], x21 = g2[lane8 + 8];
    const uint4 x30 = g3[lane8], x31 = g3[lane8 + 8];
    const uint4 x40 = g4[lane8], x41 = g4[lane8 + 8];

    float acc;
    // ---- positive: unpack a once, dot against packed c ----
    {
        float af[16];
        UNPACK_U4(a0, af, 0);
        UNPACK_U4(a1, af, 8);
        const float d = grp8_sum(dot_pk(af, c0, c1));
        acc = softplus_fast(-fminf(6.f, fmaxf(-6.f, d)));
    }
    // ---- negatives: unpack n once, 5 tree-dots, deferred reductions ----
    {
        float nf[16];
        UNPACK_U4(n0, nf, 0);
        UNPACK_U4(n1, nf, 8);
        const float d0 = grp8_sum(dot_pk(nf, x00, x01));
        const float d1 = grp8_sum(dot_pk(nf, x10, x11));
        const float d2 = grp8_sum(dot_pk(nf, x20, x21));
        const float d3 = grp8_sum(dot_pk(nf, x30, x31));
        const float d4 = grp8_sum(dot_pk(nf, x40, x41));
        acc += softplus_fast(fminf(6.f, fmaxf(-6.f, d0)));
        acc += softplus_fast(fminf(6.f, fmaxf(-6.f, d1)));
        acc += softplus_fast(fminf(6.f, fmaxf(-6.f, d2)));
        acc += softplus_fast(fminf(6.f, fmaxf(-6.f, d3)));
        acc += softplus_fast(fminf(6.f, fmaxf(-6.f, d4)));
    }

    // groups -> wave sum (each group counted once: xor8/16/32 picks one
    // representative lane per group, acc is group-uniform)
    acc += __shfl_xor(acc, 8);
    acc += __shfl_xor(acc, 16);
    acc += __shfl_xor(acc, 32);

    __shared__ float wsum[THREADS / 64];
    if ((tid & 63) == 0) wsum[tid >> 6] = acc;
    __syncthreads();
    if (tid == 0) {
        float tot = 0.f;
        #pragma unroll
        for (int w = 0; w < THREADS / 64; ++w) tot += wsum[w];
        atomicAdd(out, tot * (1.0f / (float)NPOS));
    }
}

extern "C" void kernel_launch(void* const* d_in, const int* in_sizes, int n_in,
                              void* d_out, int out_size, void* d_ws, size_t ws_size,
                              hipStream_t stream) {
    const int*   walk   = (const int*)d_in[0];
    const int*   negdst = (const int*)d_in[1];
    const float* nodeE  = (const float*)d_in[2];
    const float* ctxE   = (const float*)d_in[3];
    float*       out    = (float*)d_out;

    unsigned short* dN = (unsigned short*)d_ws;
    unsigned short* dC = dN + (size_t)NQ * EMB;

    dw_gather<<<(2 * NQ * 32) / 256, 256, 0, stream>>>(walk, nodeE, ctxE, dN, dC, out);
    dw_score<<<SBLOCKS, THREADS, 0, stream>>>(negdst, dN, dC, out);
}

// Round 14
// 39.732 us; speedup vs baseline: 1.4584x; 1.4584x over previous
//
#include <hip/hip_runtime.h>

#define WALK_LEN 40
#define WINDOW   5
#define NPAIRS   370
#define BATCHSZ  512
#define NEGK     5
#define NPOS     (BATCHSZ * NPAIRS)        // 189440
#define EMB      128
#define NQ       (BATCHSZ * WALK_LEN)      // 20480 flat-walk rows
#define THREADS  512
#define GROUPS   (THREADS / 8)             // 64 8-lane groups
#define HALFP    185                       // pairs per block (2 blocks/batch)
#define NBLOCKS  (BATCHSZ * 2)             // 1024

struct PairTab { short src[NPAIRS]; short dst[NPAIRS]; };

constexpr PairTab make_pairs() {
    PairTab t{};
    int k = 0;
    for (int i = 0; i < WALK_LEN; ++i) {
        int lo = (i - WINDOW > 0) ? (i - WINDOW) : 0;
        for (int j = lo; j < i; ++j) { t.src[k] = (short)j; t.dst[k] = (short)i; ++k; }
        int hi = (i + 1 + WINDOW < WALK_LEN) ? (i + 1 + WINDOW) : WALK_LEN;
        for (int j = i + 1; j < hi; ++j) { t.src[k] = (short)j; t.dst[k] = (short)i; ++k; }
    }
    return t;
}

__constant__ PairTab g_pairs = make_pairs();

__device__ __forceinline__ unsigned short bf16rn(float f) {
    unsigned u = __float_as_uint(f);
    u += 0x7fffu + ((u >> 16) & 1u);
    return (unsigned short)(u >> 16);
}

// fast softplus: log(1+e^x); |err| ~1e-7 for x in [-6,6]
__device__ __forceinline__ float softplus_fast(float x) {
    return __logf(1.0f + __expf(x));
}

// 8-lane-group butterfly sum, ALL-DPP (no LDS pipe, validated in R13):
// xor1, xor2 via quad_perm; ROW_HALF_MIRROR (lane^7) supplies the other
// quad's (quad-uniform) sum -> full 8-lane sum on every lane.
template <int CTRL>
__device__ __forceinline__ float dpp_add(float x) {
    int y = __builtin_amdgcn_update_dpp(0, __float_as_int(x), CTRL, 0xF, 0xF, true);
    return x + __int_as_float(y);
}
__device__ __forceinline__ float grp8_sum(float d) {
    d = dpp_add<0xB1>(d);     // quad_perm [1,0,3,2] == xor 1
    d = dpp_add<0x4E>(d);     // quad_perm [2,3,0,1] == xor 2
    d = dpp_add<0x141>(d);    // ROW_HALF_MIRROR == xor 7
    return d;
}

// unpack uint4 (8 bf16) -> 8 f32 (static indices -> registers)
#define UNPACK_U4(u, f, base)                                         \
    do {                                                              \
        _Pragma("unroll")                                             \
        for (int _i = 0; _i < 4; ++_i) {                              \
            const unsigned _v = (&(u).x)[_i];                         \
            (f)[(base) + 2 * _i]     = __uint_as_float(_v << 16);     \
            (f)[(base) + 2 * _i + 1] = __uint_as_float(_v & 0xffff0000u); \
        }                                                             \
    } while (0)

// dot of pre-unpacked 16 floats against packed bf16 rows xa,xb: 4 fma trees
__device__ __forceinline__ float dot_pk(const float* nf, uint4 xa, uint4 xb) {
    float s0 = 0.f, s1 = 0.f, s2 = 0.f, s3 = 0.f;
    #pragma unroll
    for (int i = 0; i < 4; ++i) {
        const unsigned v = (&xa.x)[i];
        s0 = fmaf(__uint_as_float(v << 16),          nf[2 * i],     s0);
        s1 = fmaf(__uint_as_float(v & 0xffff0000u),  nf[2 * i + 1], s1);
    }
    #pragma unroll
    for (int i = 0; i < 4; ++i) {
        const unsigned v = (&xb.x)[i];
        s2 = fmaf(__uint_as_float(v << 16),          nf[8 + 2 * i],     s2);
        s3 = fmaf(__uint_as_float(v & 0xffff0000u),  nf[8 + 2 * i + 1], s3);
    }
    return (s0 + s1) + (s2 + s3);
}

// ---- phase 1 (== R10): gather flat-walk rows into dense bf16, both tables ----
__global__ __launch_bounds__(256) void dw_gather(
    const int*   __restrict__ walk,
    const float* __restrict__ nodeE,
    const float* __restrict__ ctxE,
    unsigned short* __restrict__ dN,
    unsigned short* __restrict__ dC,
    float* __restrict__ out)
{
    if (blockIdx.x == 0 && threadIdx.x == 0) out[0] = 0.f;
    int idx = blockIdx.x * 256 + threadIdx.x;      // 0 .. 2*NQ*32-1
    const int is_ctx = (idx >= NQ * 32);
    if (is_ctx) idx -= NQ * 32;
    const int q = idx >> 5, c = idx & 31;
    const int row = walk[q];
    const float* src = (is_ctx ? ctxE : nodeE) + (size_t)row * EMB;
    const float4 v = *((const float4*)src + c);
    ushort4 o;
    o.x = bf16rn(v.x); o.y = bf16rn(v.y); o.z = bf16rn(v.z); o.w = bf16rn(v.w);
    unsigned short* dst = (is_ctx ? dC : dN) + (size_t)q * EMB;
    *((ushort4*)dst + c) = o;
}

// per-slot load: indices + all 10 neg-row uint4 loads issued
#define SLOT_DECL(S)                                                        \
    const int  jj##S = (S) * GROUPS + grp;                                  \
    const int  j##S  = jbase + ((jj##S < HALFP) ? jj##S : 0);               \
    const int* nb##S = negdst + ((size_t)b * NPAIRS + j##S) * NEGK;         \
    const int  qa##S = nb##S[0], qb##S = nb##S[1], qc##S = nb##S[2],        \
               qd##S = nb##S[3], qe##S = nb##S[4];                          \
    const uint4* ga##S = (const uint4*)(dC + (size_t)qa##S * EMB);          \
    const uint4* gb##S = (const uint4*)(dC + (size_t)qb##S * EMB);          \
    const uint4* gc##S = (const uint4*)(dC + (size_t)qc##S * EMB);          \
    const uint4* gd##S = (const uint4*)(dC + (size_t)qd##S * EMB);          \
    const uint4* ge##S = (const uint4*)(dC + (size_t)qe##S * EMB);          \
    const uint4 xa0##S = ga##S[lane8], xa1##S = ga##S[lane8 + 8];           \
    const uint4 xb0##S = gb##S[lane8], xb1##S = gb##S[lane8 + 8];           \
    const uint4 xc0##S = gc##S[lane8], xc1##S = gc##S[lane8 + 8];           \
    const uint4 xd0##S = gd##S[lane8], xd1##S = gd##S[lane8 + 8];           \
    const uint4 xe0##S = ge##S[lane8], xe1##S = ge##S[lane8 + 8];

#define SLOT_COMPUTE(S)                                                     \
    if (jj##S < HALFP) {                                                    \
        const int sj = g_pairs.src[j##S];                                   \
        const int dj = g_pairs.dst[j##S];                                   \
        const uint4* rN = (const uint4*)(sN + sj * 64);                     \
        const uint4* rC = (const uint4*)(sC + dj * 64);                     \
        const uint4* rS = (const uint4*)(sN + dj * 64);                     \
        const uint4 a0 = rN[lane8], a1 = rN[lane8 + 8];                     \
        const uint4 c0 = rC[lane8], c1 = rC[lane8 + 8];                     \
        const uint4 n0 = rS[lane8], n1 = rS[lane8 + 8];                     \
        float af[16];                                                       \
        UNPACK_U4(a0, af, 0); UNPACK_U4(a1, af, 8);                         \
        const float dp = grp8_sum(dot_pk(af, c0, c1));                      \
        float nf[16];                                                       \
        UNPACK_U4(n0, nf, 0); UNPACK_U4(n1, nf, 8);                         \
        const float d0 = grp8_sum(dot_pk(nf, xa0##S, xa1##S));              \
        const float d1 = grp8_sum(dot_pk(nf, xb0##S, xb1##S));              \
        const float d2 = grp8_sum(dot_pk(nf, xc0##S, xc1##S));              \
        const float d3 = grp8_sum(dot_pk(nf, xd0##S, xd1##S));              \
        const float d4 = grp8_sum(dot_pk(nf, xe0##S, xe1##S));              \
        acc += softplus_fast(-fminf(6.f, fmaxf(-6.f, dp)));                 \
        acc += softplus_fast( fminf(6.f, fmaxf(-6.f, d0)));                 \
        acc += softplus_fast( fminf(6.f, fmaxf(-6.f, d1)));                 \
        acc += softplus_fast( fminf(6.f, fmaxf(-6.f, d2)));                 \
        acc += softplus_fast( fminf(6.f, fmaxf(-6.f, d3)));                 \
        acc += softplus_fast( fminf(6.f, fmaxf(-6.f, d4)));                 \
    }

// ---- phase 2: R10 structure + 3-slot software pipeline ----
__global__ __launch_bounds__(THREADS, 2) void dw_score(
    const int* __restrict__ negdst,                 // [NPOS*NEGK] -> dense row id
    const unsigned short* __restrict__ dN,
    const unsigned short* __restrict__ dC,
    float* __restrict__ out)
{
    __shared__ unsigned int sN[WALK_LEN * 64];      // 10 KB (row = 256 B bf16)
    __shared__ unsigned int sC[WALK_LEN * 64];      // 10 KB
    __shared__ float wsum[THREADS / 64];

    const int b    = blockIdx.x >> 1;
    const int half = blockIdx.x & 1;
    const int tid  = threadIdx.x;

    {
        const uint4* srcN = (const uint4*)(dN + (size_t)b * WALK_LEN * EMB);
        const uint4* srcC = (const uint4*)(dC + (size_t)b * WALK_LEN * EMB);
        for (int u = tid; u < WALK_LEN * 16; u += THREADS) {
            ((uint4*)sN)[u] = srcN[u];
            ((uint4*)sC)[u] = srcC[u];
        }
    }
    __syncthreads();

    const int lane8 = tid & 7;
    const int grp   = tid >> 3;           // 0..63
    const int jbase = half * HALFP;
    float acc = 0.0f;

    // issue ALL 3 slots' loads first (30 uint4 in flight), then compute
    SLOT_DECL(0)
    SLOT_DECL(1)
    SLOT_DECL(2)
    SLOT_COMPUTE(0)
    SLOT_COMPUTE(1)
    SLOT_COMPUTE(2)

    // group sums -> wave sum (each group counted once)
    acc += __shfl_xor(acc, 8);
    acc += __shfl_xor(acc, 16);
    acc += __shfl_xor(acc, 32);

    if ((tid & 63) == 0) wsum[tid >> 6] = acc;
    __syncthreads();
    if (tid == 0) {
        float tot = 0.f;
        #pragma unroll
        for (int w = 0; w < THREADS / 64; ++w) tot += wsum[w];
        atomicAdd(out, tot * (1.0f / (float)NPOS));
    }
}

extern "C" void kernel_launch(void* const* d_in, const int* in_sizes, int n_in,
                              void* d_out, int out_size, void* d_ws, size_t ws_size,
                              hipStream_t stream) {
    const int*   walk   = (const int*)d_in[0];
    const int*   negdst = (const int*)d_in[1];
    const float* nodeE  = (const float*)d_in[2];
    const float* ctxE   = (const float*)d_in[3];
    float*       out    = (float*)d_out;

    unsigned short* dN = (unsigned short*)d_ws;
    unsigned short* dC = dN + (size_t)NQ * EMB;

    dw_gather<<<(2 * NQ * 32) / 256, 256, 0, stream>>>(walk, nodeE, ctxE, dN, dC, out);
    dw_score<<<NBLOCKS, THREADS, 0, stream>>>(negdst, dN, dC, out);
}